// Round 1
// baseline (495.989 us; speedup 1.0000x reference)
//
#include <hip/hip_runtime.h>
#include <hip/hip_bf16.h>

#define B_ROWS 16384
#define D_COLS 4096
#define BLOCK 256

__global__ __launch_bounds__(BLOCK) void cos_sim_kernel(
    const float* __restrict__ x1,
    const float* __restrict__ x2,
    float* __restrict__ out)
{
    const int row = blockIdx.x;
    const size_t base = (size_t)row * D_COLS;
    const float4* __restrict__ r1 = reinterpret_cast<const float4*>(x1 + base);
    const float4* __restrict__ r2 = reinterpret_cast<const float4*>(x2 + base);

    float dot = 0.0f, sx = 0.0f, sy = 0.0f;

    // D_COLS/4 = 1024 float4 per row; 256 threads -> 4 iterations each.
#pragma unroll
    for (int it = 0; it < (D_COLS / 4) / BLOCK; ++it) {
        const int j = threadIdx.x + it * BLOCK;
        float4 a = r1[j];
        float4 b = r2[j];
        dot += a.x * b.x + a.y * b.y + a.z * b.z + a.w * b.w;
        sx  += a.x * a.x + a.y * a.y + a.z * a.z + a.w * a.w;
        sy  += b.x * b.x + b.y * b.y + b.z * b.z + b.w * b.w;
    }

    // Wave-64 reduction.
#pragma unroll
    for (int off = 32; off > 0; off >>= 1) {
        dot += __shfl_down(dot, off, 64);
        sx  += __shfl_down(sx,  off, 64);
        sy  += __shfl_down(sy,  off, 64);
    }

    __shared__ float sred[3][BLOCK / 64];
    const int wave = threadIdx.x >> 6;
    const int lane = threadIdx.x & 63;
    if (lane == 0) {
        sred[0][wave] = dot;
        sred[1][wave] = sx;
        sred[2][wave] = sy;
    }
    __syncthreads();

    if (threadIdx.x == 0) {
        float d = 0.0f, a = 0.0f, b = 0.0f;
#pragma unroll
        for (int w = 0; w < BLOCK / 64; ++w) {
            d += sred[0][w];
            a += sred[1][w];
            b += sred[2][w];
        }
        out[row] = 0.5f * d / (sqrtf(a) * sqrtf(b));
    }
}

extern "C" void kernel_launch(void* const* d_in, const int* in_sizes, int n_in,
                              void* d_out, int out_size, void* d_ws, size_t ws_size,
                              hipStream_t stream) {
    const float* x1 = (const float*)d_in[0];
    const float* x2 = (const float*)d_in[1];
    float* out = (float*)d_out;

    cos_sim_kernel<<<B_ROWS, BLOCK, 0, stream>>>(x1, x2, out);
}

// Round 2
// 468.324 us; speedup vs baseline: 1.0591x; 1.0591x over previous
//
#include <hip/hip_runtime.h>
#include <hip/hip_bf16.h>

#define B_ROWS 16384
#define D_COLS 4096
#define BLOCK 256
#define WAVES_PER_BLOCK (BLOCK / 64)
// One wave per row: 4096 float/row = 1024 float4 / 64 lanes = 16 float4 per lane per input.
#define F4_PER_LANE (D_COLS / 4 / 64)

typedef float f32x4 __attribute__((ext_vector_type(4)));

__global__ __launch_bounds__(BLOCK) void cos_sim_kernel(
    const float* __restrict__ x1,
    const float* __restrict__ x2,
    float* __restrict__ out)
{
    const int wave = threadIdx.x >> 6;
    const int lane = threadIdx.x & 63;
    const int row  = blockIdx.x * WAVES_PER_BLOCK + wave;
    const size_t base = (size_t)row * D_COLS;

    const f32x4* __restrict__ r1 = reinterpret_cast<const f32x4*>(x1 + base);
    const f32x4* __restrict__ r2 = reinterpret_cast<const f32x4*>(x2 + base);

    float dot = 0.0f, sx = 0.0f, sy = 0.0f;

#pragma unroll
    for (int it = 0; it < F4_PER_LANE; ++it) {
        f32x4 a = __builtin_nontemporal_load(&r1[lane + it * 64]);
        f32x4 b = __builtin_nontemporal_load(&r2[lane + it * 64]);
        dot += a.x * b.x + a.y * b.y + a.z * b.z + a.w * b.w;
        sx  += a.x * a.x + a.y * a.y + a.z * a.z + a.w * a.w;
        sy  += b.x * b.x + b.y * b.y + b.z * b.z + b.w * b.w;
    }

    // Wave-64 butterfly reduction — no LDS, no barrier.
#pragma unroll
    for (int off = 32; off > 0; off >>= 1) {
        dot += __shfl_down(dot, off, 64);
        sx  += __shfl_down(sx,  off, 64);
        sy  += __shfl_down(sy,  off, 64);
    }

    if (lane == 0) {
        out[row] = 0.5f * dot / (sqrtf(sx) * sqrtf(sy));
    }
}

extern "C" void kernel_launch(void* const* d_in, const int* in_sizes, int n_in,
                              void* d_out, int out_size, void* d_ws, size_t ws_size,
                              hipStream_t stream) {
    const float* x1 = (const float*)d_in[0];
    const float* x2 = (const float*)d_in[1];
    float* out = (float*)d_out;

    cos_sim_kernel<<<B_ROWS / WAVES_PER_BLOCK, BLOCK, 0, stream>>>(x1, x2, out);
}

// Round 3
// 464.170 us; speedup vs baseline: 1.0686x; 1.0090x over previous
//
#include <hip/hip_runtime.h>
#include <hip/hip_bf16.h>

#define B_ROWS 16384
#define D_COLS 4096
#define BLOCK 256
#define WAVES_PER_BLOCK (BLOCK / 64)
// One wave per row: 4096 float/row = 1024 float4 / 64 lanes = 16 float4 per lane per input.
#define F4_PER_LANE (D_COLS / 4 / 64)

typedef float f32x4 __attribute__((ext_vector_type(4)));

__global__ __launch_bounds__(BLOCK, 4) void cos_sim_kernel(
    const float* __restrict__ x1,
    const float* __restrict__ x2,
    float* __restrict__ out)
{
    const int wave = threadIdx.x >> 6;
    const int lane = threadIdx.x & 63;
    const int row  = blockIdx.x * WAVES_PER_BLOCK + wave;
    const size_t base = (size_t)row * D_COLS;

    const f32x4* __restrict__ r1 = reinterpret_cast<const f32x4*>(x1 + base);
    const f32x4* __restrict__ r2 = reinterpret_cast<const f32x4*>(x2 + base);

    float dot = 0.0f, sx = 0.0f, sy = 0.0f;

    // Partial unroll: ~8 float4 loads in flight instead of 32 -> lower VGPR
    // pressure -> more resident waves to hide HBM latency.
#pragma unroll 4
    for (int it = 0; it < F4_PER_LANE; ++it) {
        f32x4 a = __builtin_nontemporal_load(&r1[lane + it * 64]);
        f32x4 b = __builtin_nontemporal_load(&r2[lane + it * 64]);
        dot += a.x * b.x + a.y * b.y + a.z * b.z + a.w * b.w;
        sx  += a.x * a.x + a.y * a.y + a.z * a.z + a.w * a.w;
        sy  += b.x * b.x + b.y * b.y + b.z * b.z + b.w * b.w;
    }

    // Wave-64 butterfly reduction — no LDS, no barrier.
#pragma unroll
    for (int off = 32; off > 0; off >>= 1) {
        dot += __shfl_down(dot, off, 64);
        sx  += __shfl_down(sx,  off, 64);
        sy  += __shfl_down(sy,  off, 64);
    }

    if (lane == 0) {
        out[row] = 0.5f * dot / (sqrtf(sx) * sqrtf(sy));
    }
}

extern "C" void kernel_launch(void* const* d_in, const int* in_sizes, int n_in,
                              void* d_out, int out_size, void* d_ws, size_t ws_size,
                              hipStream_t stream) {
    const float* x1 = (const float*)d_in[0];
    const float* x2 = (const float*)d_in[1];
    float* out = (float*)d_out;

    cos_sim_kernel<<<B_ROWS / WAVES_PER_BLOCK, BLOCK, 0, stream>>>(x1, x2, out);
}